// Round 9
// baseline (215.080 us; speedup 1.0000x reference)
//
#include <hip/hip_runtime.h>
#include <hip/hip_bf16.h>

#define N_NODES 40000
#define N_EDGES 640000
#define D_IN 512
#define D_OUT 128
#define BM 128
#define BK 64
#define CAP1 64          // level-1 hash slots/row (plain stores, slot = e & 63)
#define CAP2 12          // level-2 loser slots/row (atomic cursor, ~71k total losers)
#define OVF_MAX 8192
#define NB_GE 313        // gemm blocks (128-row tiles)
#define NB_HS 313        // hashstore blocks (2048 edges each)
#define NB_VF 625        // verify blocks (1024 edges each)

typedef __attribute__((ext_vector_type(4))) float f32x4;
typedef __attribute__((ext_vector_type(8))) short bf16x8;
typedef __attribute__((ext_vector_type(4))) unsigned short us4;

static __device__ __forceinline__ unsigned short f2bf(float f) {
    unsigned int u = __float_as_uint(f);
    unsigned int r = u + 0x7fffu + ((u >> 16) & 1u);   // RNE
    return (unsigned short)(r >> 16);
}

// ---------------------------------------------------------------------------
// prep: zero bucket1 + bucket2 + cursor2 + ovf (12.45 MB, int4 grid-stride)
// ---------------------------------------------------------------------------
__global__ __launch_bounds__(256) void prep_kernel(int4* __restrict__ zbase, int nz4)
{
    const int stride = 512 * 256;
    for (int i = blockIdx.x * 256 + threadIdx.x; i < nz4; i += stride)
        zbase[i] = make_int4(0, 0, 0, 0);
}

// ---------------------------------------------------------------------------
// fused: blocks [0, NB_GE) = LDS-tiled MFMA GEMM (R3-proven, unchanged);
//        blocks [NB_GE, ..) = ATOMIC-FREE hash store: bucket1[row][e&63]=e+1.
//        One winner per slot survives; losers detected in verify_kernel.
// ---------------------------------------------------------------------------
__global__ __launch_bounds__(256) void fused_kernel(
    const float* __restrict__ x, const float* __restrict__ w,
    unsigned short* __restrict__ seq,
    const int* __restrict__ erow, unsigned int* __restrict__ bucket1)
{
    if (blockIdx.x >= NB_GE) {
        const int base = (blockIdx.x - NB_GE) * 2048 + threadIdx.x;
        #pragma unroll
        for (int j = 0; j < 8; j++) {
            int e = base + j * 256;
            if (e < N_EDGES) {
                int r = erow[e];
                bucket1[(size_t)r * CAP1 + (e & 63)] = (unsigned int)(e + 1);
            }
        }
        return;
    }

    // ---- GEMM: seq[n][o] = sum_i x[n][i]*w[o][i], bf16 out ----
    __shared__ unsigned short As[BM * BK];     // 16 KB
    __shared__ unsigned short Bs[D_OUT * BK];  // 16 KB

    const int tid = threadIdx.x;
    const int lane = tid & 63;
    const int wv = tid >> 6;
    const int block_row = blockIdx.x * BM;
    const int srow = tid >> 3;               // 0..31
    const int scol = (tid & 7) * 8;          // 0..56

    f32x4 ra[4][2], rb[4][2];                // prefetch regs

    auto issue_loads = [&](int k0) {
        #pragma unroll
        for (int p = 0; p < 4; ++p) {
            int gr = block_row + srow + p * 32; if (gr >= N_NODES) gr = N_NODES - 1;
            const float* sa = x + (size_t)gr * D_IN + k0 + scol;
            ra[p][0] = *(const f32x4*)sa;
            ra[p][1] = *(const f32x4*)(sa + 4);
            const float* sb = w + (size_t)(srow + p * 32) * D_IN + k0 + scol;
            rb[p][0] = *(const f32x4*)sb;
            rb[p][1] = *(const f32x4*)(sb + 4);
        }
    };

    f32x4 acc[2][8];
    #pragma unroll
    for (int i = 0; i < 2; i++)
        #pragma unroll
        for (int j = 0; j < 8; j++)
            acc[i][j] = f32x4{0.f, 0.f, 0.f, 0.f};

    issue_loads(0);

    for (int kt = 0; kt < D_IN / BK; ++kt) {
        __syncthreads();
        #pragma unroll
        for (int p = 0; p < 4; ++p) {
            int r = srow + p * 32;
            us4 h0, h1, g0, g1;
            #pragma unroll
            for (int q = 0; q < 4; q++) {
                h0[q] = f2bf(ra[p][0][q]); h1[q] = f2bf(ra[p][1][q]);
                g0[q] = f2bf(rb[p][0][q]); g1[q] = f2bf(rb[p][1][q]);
            }
            int off = (r * (BK * 2) + scol * 2) ^ ((r & 7) << 4);
            *(us4*)((char*)As + off)     = h0;
            *(us4*)((char*)As + off + 8) = h1;
            *(us4*)((char*)Bs + off)     = g0;
            *(us4*)((char*)Bs + off + 8) = g1;
        }
        if (kt < D_IN / BK - 1) issue_loads((kt + 1) * BK);  // overlap w/ MFMA
        __syncthreads();

        #pragma unroll
        for (int ks = 0; ks < 2; ++ks) {
            const int kb = ks * 32 + (lane >> 4) * 8;
            bf16x8 a[2], b[8];
            #pragma unroll
            for (int m = 0; m < 2; m++) {
                int r = wv * 32 + m * 16 + (lane & 15);
                int off = (r * (BK * 2) + kb * 2) ^ ((r & 7) << 4);
                a[m] = *(const bf16x8*)((const char*)As + off);
            }
            #pragma unroll
            for (int n = 0; n < 8; n++) {
                int r = n * 16 + (lane & 15);
                int off = (r * (BK * 2) + kb * 2) ^ ((r & 7) << 4);
                b[n] = *(const bf16x8*)((const char*)Bs + off);
            }
            #pragma unroll
            for (int m = 0; m < 2; m++)
                #pragma unroll
                for (int n = 0; n < 8; n++)
                    acc[m][n] = __builtin_amdgcn_mfma_f32_16x16x32_bf16(a[m], b[n], acc[m][n], 0, 0, 0);
        }
    }

    // C/D layout: col=lane&15, row=(lane>>4)*4+reg  [measured m89]
    #pragma unroll
    for (int m = 0; m < 2; m++) {
        #pragma unroll
        for (int r = 0; r < 4; r++) {
            int grow = block_row + wv * 32 + m * 16 + (lane >> 4) * 4 + r;
            if (grow < N_NODES) {
                #pragma unroll
                for (int n = 0; n < 8; n++) {
                    int col = n * 16 + (lane & 15);
                    seq[(size_t)grow * D_OUT + col] = f2bf(acc[m][n][r]);
                }
            }
        }
    }
}

// ---------------------------------------------------------------------------
// verify: edge e lost iff bucket1[row][e&63] != e+1 (kernel boundary made all
// stores visible). Losers (~11%) append to bucket2 via atomic cursor.
// ---------------------------------------------------------------------------
__global__ __launch_bounds__(256) void verify_kernel(
    const int* __restrict__ erow, const int* __restrict__ ecol,
    const float* __restrict__ eval, const unsigned int* __restrict__ bucket1,
    int* __restrict__ cursor2, unsigned int* __restrict__ bucket2,
    int* __restrict__ ovf_cnt, int4* __restrict__ ovf)
{
    const int base = blockIdx.x * 1024 + threadIdx.x;
    int r[4];
    unsigned int id[4];
    #pragma unroll
    for (int j = 0; j < 4; j++) {
        int e = base + j * 256;
        r[j] = erow[e];
        id[j] = bucket1[(size_t)r[j] * CAP1 + (e & 63)];
    }
    #pragma unroll
    for (int j = 0; j < 4; j++) {
        int e = base + j * 256;
        if (id[j] != (unsigned int)(e + 1)) {
            int c = ecol[e];
            float v = eval[e];
            int s2 = atomicAdd(&cursor2[r[j]], 1);
            if (s2 < CAP2) {
                bucket2[(size_t)r[j] * CAP2 + s2] =
                    ((unsigned int)f2bf(v) << 16) | (unsigned int)c;
            } else {
                int o = atomicAdd(ovf_cnt, 1);
                if (o < OVF_MAX) ovf[o] = make_int4(r[j], c, __float_as_int(v), 0);
            }
        }
    }
}

// ---------------------------------------------------------------------------
// agg: one wave per row. Lane l reads L1 slot l (coalesced 256B), ballot ->
// occupancy mask, iterate set bits 4-wide: shfl edge-id, uniform col/val
// loads, per-lane seq gather. Then L2 bucket (packed, zero-safe) + ovf net.
// ---------------------------------------------------------------------------
__global__ __launch_bounds__(256) void agg_kernel(
    const unsigned short* __restrict__ seq, const int* __restrict__ ecol,
    const float* __restrict__ eval, const unsigned int* __restrict__ bucket1,
    const int* __restrict__ cursor2, const unsigned int* __restrict__ bucket2,
    const int* __restrict__ ovf_cnt, const int4* __restrict__ ovf,
    const float* __restrict__ bias, const float* __restrict__ alpha,
    float* __restrict__ out)
{
    const int row = blockIdx.x * 4 + (threadIdx.x >> 6);
    const int lane = threadIdx.x & 63;

    unsigned int myid = bucket1[(size_t)row * CAP1 + lane];
    unsigned long long mask = __ballot(myid != 0);

    float a0 = 0.f, a1 = 0.f;
    while (mask) {
        int b0 = __builtin_ctzll(mask); mask &= mask - 1;
        int b1 = -1, b2 = -1, b3 = -1;
        if (mask) { b1 = __builtin_ctzll(mask); mask &= mask - 1; }
        if (mask) { b2 = __builtin_ctzll(mask); mask &= mask - 1; }
        if (mask) { b3 = __builtin_ctzll(mask); mask &= mask - 1; }
        int i0 = (int)__shfl(myid, b0) - 1;
        int i1 = (int)__shfl(myid, b1 < 0 ? b0 : b1) - 1;
        int i2 = (int)__shfl(myid, b2 < 0 ? b0 : b2) - 1;
        int i3 = (int)__shfl(myid, b3 < 0 ? b0 : b3) - 1;
        int c0 = ecol[i0], c1 = ecol[i1], c2 = ecol[i2], c3 = ecol[i3];
        float v0 = eval[i0];
        float v1 = b1 >= 0 ? eval[i1] : 0.f;
        float v2 = b2 >= 0 ? eval[i2] : 0.f;
        float v3 = b3 >= 0 ? eval[i3] : 0.f;
        unsigned int p0 = *(const unsigned int*)(seq + ((size_t)c0 << 7) + lane * 2);
        unsigned int p1 = *(const unsigned int*)(seq + ((size_t)c1 << 7) + lane * 2);
        unsigned int p2 = *(const unsigned int*)(seq + ((size_t)c2 << 7) + lane * 2);
        unsigned int p3 = *(const unsigned int*)(seq + ((size_t)c3 << 7) + lane * 2);
        a0 += v0 * __uint_as_float(p0 << 16);
        a1 += v0 * __uint_as_float(p0 & 0xffff0000u);
        a0 += v1 * __uint_as_float(p1 << 16);
        a1 += v1 * __uint_as_float(p1 & 0xffff0000u);
        a0 += v2 * __uint_as_float(p2 << 16);
        a1 += v2 * __uint_as_float(p2 & 0xffff0000u);
        a0 += v3 * __uint_as_float(p3 << 16);
        a1 += v3 * __uint_as_float(p3 & 0xffff0000u);
    }

    // level-2 losers (packed bf16|col, zero-init -> overrun-safe chunks)
    int cnt2 = cursor2[row];
    int mx2 = cnt2 < CAP2 ? cnt2 : CAP2;
    const unsigned int* bk2 = bucket2 + (size_t)row * CAP2;
    for (int s = 0; s < mx2; s += 4) {
        #pragma unroll
        for (int j = 0; j < 4; j++) {
            unsigned int q = bk2[s + j];
            float vv = __uint_as_float(q & 0xffff0000u);
            int col = q & 0xffff;
            unsigned int p = *(const unsigned int*)(seq + ((size_t)col << 7) + lane * 2);
            a0 += vv * __uint_as_float(p << 16);
            a1 += vv * __uint_as_float(p & 0xffff0000u);
        }
    }

    int on = *ovf_cnt;
    on = on < OVF_MAX ? on : OVF_MAX;
    for (int i = 0; i < on; ++i) {
        int4 t = ovf[i];
        if (t.x == row) {
            float vv = __int_as_float(t.z);
            unsigned int p = *(const unsigned int*)(seq + ((size_t)t.y << 7) + lane * 2);
            a0 += vv * __uint_as_float(p << 16);
            a1 += vv * __uint_as_float(p & 0xffff0000u);
        }
    }

    float al = alpha[0];
    float2 bi = *(const float2*)(bias + lane * 2);
    float r0 = a0 + bi.x;
    float r1 = a1 + bi.y;
    r0 = r0 > 0.f ? r0 : al * r0;
    r1 = r1 > 0.f ? r1 : al * r1;
    *(float2*)(out + (size_t)row * D_OUT + lane * 2) = make_float2(r0, r1);
}

// ---------------------------------------------------------------------------
extern "C" void kernel_launch(void* const* d_in, const int* in_sizes, int n_in,
                              void* d_out, int out_size, void* d_ws, size_t ws_size,
                              hipStream_t stream)
{
    (void)in_sizes; (void)n_in; (void)out_size; (void)ws_size;
    const float* x     = (const float*)d_in[0];
    const float* w     = (const float*)d_in[1];
    const float* bias  = (const float*)d_in[2];
    const float* alpha = (const float*)d_in[3];
    const float* eval  = (const float*)d_in[4];
    const int*   erow  = (const int*)d_in[5];
    const int*   ecol  = (const int*)d_in[6];
    float* out = (float*)d_out;

    char* ws = (char*)d_ws;
    unsigned short* seq     = (unsigned short*)ws;            // 10,240,000 B
    unsigned int*   bucket1 = (unsigned int*)(ws + 10240000); // 10,240,000 B (40000*64*4)
    unsigned int*   bucket2 = (unsigned int*)(ws + 20480000); //  1,920,000 B (40000*12*4)
    int*  cursor2 = (int*)(ws + 22400000);                    //    160,000 B
    int*  ovf_cnt = (int*)(ws + 22560000);                    //         16 B
    int4* ovf     = (int4*)(ws + 22560016);                   //    131,072 B

    // zero region: bucket1..ovf end = 12,451,088 B = 778,193 int4
    const int nz4 = 778193;
    prep_kernel<<<512, 256, 0, stream>>>((int4*)(ws + 10240000), nz4);
    fused_kernel<<<NB_GE + NB_HS, 256, 0, stream>>>(x, w, seq, erow, bucket1);
    verify_kernel<<<NB_VF, 256, 0, stream>>>(erow, ecol, eval, bucket1,
                                             cursor2, bucket2, ovf_cnt, ovf);
    agg_kernel<<<N_NODES / 4, 256, 0, stream>>>(seq, ecol, eval, bucket1, cursor2,
                                                bucket2, ovf_cnt, ovf, bias, alpha, out);
}